// Round 2
// baseline (297.868 us; speedup 1.0000x reference)
//
#include <hip/hip_runtime.h>

#define N_NODES 100000
#define DEG 16
#define IN_F 128
#define OUT_F 64
#define E_EDGES (N_NODES * DEG)
#define SLICE_U32 (N_NODES * 8)   // u32 elements per column-slice image

typedef __bf16 bf16x8 __attribute__((ext_vector_type(8)));
typedef unsigned short u16x8 __attribute__((ext_vector_type(8)));
typedef float f32x4 __attribute__((ext_vector_type(4)));
typedef float f32x2 __attribute__((ext_vector_type(2)));
typedef unsigned int u32x4 __attribute__((ext_vector_type(4)));

union BF8 { u16x8 u; bf16x8 b; };

__device__ inline float lo_bf(unsigned int u) {
    union { unsigned int i; float f; } v; v.i = u << 16; return v.f;
}
__device__ inline float hi_bf(unsigned int u) {
    union { unsigned int i; float f; } v; v.i = u & 0xFFFF0000u; return v.f;
}
__device__ inline unsigned short f2bf(float f) {
    union { float f; unsigned int i; } v; v.f = f;
    return (unsigned short)((v.i + 0x7FFFu + ((v.i >> 16) & 1u)) >> 16);
}
__device__ inline unsigned int packbf(float a, float b) {
    return (unsigned int)f2bf(a) | ((unsigned int)f2bf(b) << 16);
}

// ---------------- Kernel W: build pre-swizzled bf16 W image (LDS layout) ----
// Wimg: [2][64][136] u16; [m][n][k] = bf16(W_m[k*64 + n])   (W^T, stride 136)
__global__ __launch_bounds__(256) void k_wprep(
    const float* __restrict__ Wh, const float* __restrict__ Wl,
    unsigned short* __restrict__ Wimg)
{
    int idx = blockIdx.x * 256 + threadIdx.x;      // 64 blocks -> 16384 threads
    int m = idx >> 13;
    int rem = idx & 8191;
    int k = rem >> 6, n = rem & 63;
    float v = m ? Wl[rem] : Wh[rem];
    Wimg[m * 8704 + n * 136 + k] = f2bf(v);
}

// ---------------- Kernel A: GEMM -> slice-major H (round-0 math exactly) ----
// Hs: [8 slices][N][8] u32, Hs[col>>3][row][col&7] = pack(bf16 h_high, bf16 h_low)
__global__ __launch_bounds__(256) void k_gemm(
    const float* __restrict__ in, const unsigned short* __restrict__ Wimg,
    unsigned int* __restrict__ Hs)
{
    __shared__ __align__(16) unsigned short ldsW[2][64][136];  // 34816 B
    __shared__ __align__(16) unsigned short ldsA[64][136];     // 17408 B

    // W image: 2176 x 16B chunks, straight copy
    {
        const u32x4* src = (const u32x4*)Wimg;
        u32x4* dst = (u32x4*)ldsW;
        for (int i = threadIdx.x; i < 2176; i += 256) dst[i] = src[i];
    }

    // A tile: 64 rows x 128 f32, fully coalesced f32x4 loads, packed LDS writes
    int row0B = blockIdx.x * 64;
    {
        const f32x4* src = (const f32x4*)(in + (size_t)row0B * IN_F);
        #pragma unroll
        for (int i = 0; i < 8; i++) {
            int cch = threadIdx.x + 256 * i;         // 2048 chunks of f32x4
            int row = cch >> 5;                      // 32 chunks per row
            int kc = (cch & 31) * 4;
            int grow = row0B + row;
            f32x4 v = (grow < N_NODES) ? src[cch]
                      : *(const f32x4*)(in + (size_t)(N_NODES - 1) * IN_F + kc);
            unsigned int p0 = packbf(v[0], v[1]);
            unsigned int p1 = packbf(v[2], v[3]);
            *(unsigned int*)&ldsA[row][kc]     = p0;
            *(unsigned int*)&ldsA[row][kc + 2] = p1;
        }
    }
    __syncthreads();

    int wv = threadIdx.x >> 6;
    int lane = threadIdx.x & 63;
    int quad = lane >> 4, c = lane & 15;
    int row0 = row0B + wv * 16;

    bf16x8 afrag[4];
    #pragma unroll
    for (int kb = 0; kb < 4; kb++) {
        BF8 a;
        a.u = *(const u16x8*)&ldsA[wv * 16 + c][kb * 32 + quad * 8];
        afrag[kb] = a.b;
    }

    f32x4 acc[2][4];
    #pragma unroll
    for (int m = 0; m < 2; m++)
        #pragma unroll
        for (int t = 0; t < 4; t++) acc[m][t] = (f32x4){0, 0, 0, 0};

    #pragma unroll
    for (int kb = 0; kb < 4; kb++) {
        #pragma unroll
        for (int t = 0; t < 4; t++) {
            int n = t * 16 + c;
            BF8 bh, bl;
            bh.u = *(const u16x8*)&ldsW[0][n][kb * 32 + quad * 8];
            bl.u = *(const u16x8*)&ldsW[1][n][kb * 32 + quad * 8];
            acc[0][t] = __builtin_amdgcn_mfma_f32_16x16x32_bf16(afrag[kb], bh.b, acc[0][t], 0, 0, 0);
            acc[1][t] = __builtin_amdgcn_mfma_f32_16x16x32_bf16(afrag[kb], bl.b, acc[1][t], 0, 0, 0);
        }
    }

    // C/D: col = t*16 + c, row = quad*4 + r  (proven mapping); sliced store
    #pragma unroll
    for (int r = 0; r < 4; r++) {
        int row = row0 + quad * 4 + r;
        if (row >= N_NODES) continue;
        #pragma unroll
        for (int t = 0; t < 4; t++) {
            int col = t * 16 + c;
            Hs[(size_t)(col >> 3) * SLICE_U32 + (size_t)row * 8 + (col & 7)]
                = packbf(acc[0][t][r], acc[1][t][r]);
        }
    }
}

// ---------------- Kernel S: attention scalars, old-k_agg numerics exactly ----
__global__ __launch_bounds__(256) void k_s(
    const unsigned int* __restrict__ Hs, const float* __restrict__ ah,
    const float* __restrict__ al, f32x4* __restrict__ s)
{
    int lane = threadIdx.x & 63;
    int node = __builtin_amdgcn_readfirstlane(blockIdx.x * 4 + (threadIdx.x >> 6));
    // col = lane: slice = lane>>3, pos = lane&7
    unsigned int hu = Hs[(size_t)(lane >> 3) * SLICE_U32 + (size_t)node * 8 + (lane & 7)];
    float hh = lo_bf(hu);
    float hl = hi_bf(hu);
    float ph = hh * ah[lane];
    float qh = hh * ah[64 + lane];
    float pl = hl * al[lane];
    float ql = hl * al[64 + lane];
    #pragma unroll
    for (int o = 32; o > 0; o >>= 1) {
        ph += __shfl_xor(ph, o);
        qh += __shfl_xor(qh, o);
        pl += __shfl_xor(pl, o);
        ql += __shfl_xor(ql, o);
    }
    if (lane == 0) s[node] = (f32x4){ph, qh, pl, ql};
}

// ---------------- Kernel B: sliced HAGG, old-k_agg accumulation order ----
// blockIdx%8 = slice; each thread owns (node, col=slice*8+c)
__global__ __launch_bounds__(256) void k_aggh(
    const unsigned int* __restrict__ Hs, const int* __restrict__ dst,
    unsigned int* __restrict__ HAGGs)
{
    int slice = blockIdx.x & 7;
    int nb = blockIdx.x >> 3;
    int lane = threadIdx.x & 63;
    int wid = threadIdx.x >> 6;
    int c = lane & 7;
    int node = nb * 32 + wid * 8 + (lane >> 3);
    const unsigned int* base = Hs + (size_t)slice * SLICE_U32;
    const int* dp = dst + node * DEG;

    unsigned int hu = base[(size_t)node * 8 + c];   // own row, same col
    float sh = 16.0f * lo_bf(hu);
    float sl = 16.0f * hi_bf(hu);

    #pragma unroll
    for (int half = 0; half < 2; half++) {
        unsigned int u[8];
        #pragma unroll
        for (int t = 0; t < 8; t++) {
            int j = dp[half * 8 + t];
            u[t] = base[(size_t)j * 8 + c];
        }
        #pragma unroll
        for (int t = 0; t < 8; t++) { sh += lo_bf(u[t]); sl -= hi_bf(u[t]); }
    }
    HAGGs[(size_t)slice * SLICE_U32 + (size_t)node * 8 + c] = packbf(sh, sl);
}

// ---------------- Kernel E: per-edge raw weights + per-node rowsums ----
// We[g] = (relu6(eh), relu6(el));  R[i] = (rh, rl) rowsums of RAW exp values
__global__ __launch_bounds__(256) void k_edge(
    const int* __restrict__ dst, const f32x4* __restrict__ s,
    f32x2* __restrict__ We, f32x2* __restrict__ R)
{
    int g = blockIdx.x * 256 + threadIdx.x;   // edge id; 16 lanes per node
    int i = g >> 4;
    int j = dst[g];
    f32x4 si = s[i];
    f32x4 sj = s[j];
    float xh = si[0] + sj[1];                 // p_high[i] + q_high[j]
    float xl = si[2] + sj[3];
    float lh = xh > 0.0f ? xh : 0.2f * xh;
    float ll = xl > 0.0f ? xl : 0.2f * xl;
    float wh = __expf(-lh);
    float wl = __expf(-ll);
    float rh = wh, rl = wl;
    #pragma unroll
    for (int o = 8; o > 0; o >>= 1) { rh += __shfl_xor(rh, o); rl += __shfl_xor(rl, o); }
    We[g] = (f32x2){fminf(wh, 6.0f), fminf(wl, 6.0f)};
    if ((g & 15) == 0) R[i] = (f32x2){rh, rl};
}

// ---------------- Kernel C: sliced weighted aggregate, old-k_out numerics ----
__global__ __launch_bounds__(256) void k_out(
    const unsigned int* __restrict__ HAGGs, const int* __restrict__ dst,
    const f32x2* __restrict__ We, const f32x2* __restrict__ R,
    float* __restrict__ out)
{
    int slice = blockIdx.x & 7;
    int nb = blockIdx.x >> 3;
    int lane = threadIdx.x & 63;
    int wid = threadIdx.x >> 6;
    int c = lane & 7;
    int node = nb * 32 + wid * 8 + (lane >> 3);
    const unsigned int* base = HAGGs + (size_t)slice * SLICE_U32;
    const int* dp = dst + node * DEG;
    const f32x4* wp = (const f32x4*)(We + node * DEG);   // 2 edges per f32x4
    f32x2 rr = R[node];

    float acc_h = 0.0f, acc_l = 0.0f;
    #pragma unroll
    for (int half = 0; half < 2; half++) {
        unsigned int u[8];
        #pragma unroll
        for (int t = 0; t < 8; t++) {
            int j = dp[half * 8 + t];
            u[t] = base[(size_t)j * 8 + c];
        }
        f32x4 w0 = wp[half * 4],     w1 = wp[half * 4 + 1];
        f32x4 w2 = wp[half * 4 + 2], w3 = wp[half * 4 + 3];
        acc_h += w0[0] * lo_bf(u[0]);  acc_l += w0[1] * hi_bf(u[0]);
        acc_h += w0[2] * lo_bf(u[1]);  acc_l += w0[3] * hi_bf(u[1]);
        acc_h += w1[0] * lo_bf(u[2]);  acc_l += w1[1] * hi_bf(u[2]);
        acc_h += w1[2] * lo_bf(u[3]);  acc_l += w1[3] * hi_bf(u[3]);
        acc_h += w2[0] * lo_bf(u[4]);  acc_l += w2[1] * hi_bf(u[4]);
        acc_h += w2[2] * lo_bf(u[5]);  acc_l += w2[3] * hi_bf(u[5]);
        acc_h += w3[0] * lo_bf(u[6]);  acc_l += w3[1] * hi_bf(u[6]);
        acc_h += w3[2] * lo_bf(u[7]);  acc_l += w3[3] * hi_bf(u[7]);
    }
    float r = 0.5f * (acc_h / rr[0] + acc_l / rr[1]);
    r = fminf(fmaxf(r, 0.0f), 6.0f);
    out[(size_t)node * OUT_F + slice * 8 + c] = r;
}

extern "C" void kernel_launch(void* const* d_in, const int* in_sizes, int n_in,
                              void* d_out, int out_size, void* d_ws, size_t ws_size,
                              hipStream_t stream) {
    const float* input = (const float*)d_in[0];
    const int*   edge  = (const int*)d_in[1];     // [2, E]: src then dst
    const float* Wh    = (const float*)d_in[2];
    const float* Wl    = (const float*)d_in[3];
    const float* ah    = (const float*)d_in[4];
    const float* al    = (const float*)d_in[5];
    float* out = (float*)d_out;

    // workspace: [Hs 25.6MB | HAGGs 25.6MB | s 1.6MB | Wimg 34.8KB]  (= round-0 size)
    // We (12.8MB) + R (0.8MB) alias Hs: written by k_edge AFTER k_s/k_aggh consumed Hs.
    unsigned int* Hs    = (unsigned int*)d_ws;
    unsigned int* HAGGs = Hs + (size_t)8 * SLICE_U32;
    f32x4* s = (f32x4*)(HAGGs + (size_t)8 * SLICE_U32);
    unsigned short* Wimg = (unsigned short*)(s + N_NODES);
    f32x2* We = (f32x2*)d_ws;
    f32x2* R  = (f32x2*)d_ws + E_EDGES;

    const int* dstp = edge + E_EDGES;

    k_wprep<<<64, 256, 0, stream>>>(Wh, Wl, Wimg);
    k_gemm<<<1563, 256, 0, stream>>>(input, Wimg, Hs);
    k_s<<<N_NODES / 4, 256, 0, stream>>>(Hs, ah, al, s);
    k_aggh<<<25000, 256, 0, stream>>>(Hs, dstp, HAGGs);
    k_edge<<<6250, 256, 0, stream>>>(dstp, s, We, R);
    k_out<<<25000, 256, 0, stream>>>(HAGGs, dstp, We, R, out);
}

// Round 3
// 228.575 us; speedup vs baseline: 1.3032x; 1.3032x over previous
//
#include <hip/hip_runtime.h>

#define N_NODES 100000
#define DEG 16
#define IN_F 128
#define OUT_F 64
#define E_EDGES (N_NODES * DEG)

typedef __bf16 bf16x8 __attribute__((ext_vector_type(8)));
typedef unsigned short u16x8 __attribute__((ext_vector_type(8)));
typedef float f32x4 __attribute__((ext_vector_type(4)));
typedef unsigned int u32x4 __attribute__((ext_vector_type(4)));

union BF8 { u16x8 u; bf16x8 b; };

__device__ inline float lo_bf(unsigned int u) {
    union { unsigned int i; float f; } v; v.i = u << 16; return v.f;
}
__device__ inline float hi_bf(unsigned int u) {
    union { unsigned int i; float f; } v; v.i = u & 0xFFFF0000u; return v.f;
}
__device__ inline unsigned short f2bf(float f) {
    union { float f; unsigned int i; } v; v.f = f;
    return (unsigned short)((v.i + 0x7FFFu + ((v.i >> 16) & 1u)) >> 16);
}
__device__ inline unsigned int packbf(float a, float b) {
    return (unsigned int)f2bf(a) | ((unsigned int)f2bf(b) << 16);
}

// ---------------- Kernel A: fused W-swizzle + GEMM -> row-major H ----------
// ldsW: [m][n][k] = bf16(W_m[k*64 + n])  (W^T image, stride 136, same as the
// old k_wprep Wimg — built in-block from the L2-resident 64 KB W matrices)
// H[row*64 + col] = pack(bf16 h_high, bf16 h_low)   (round-0 layout/numerics)
__global__ __launch_bounds__(256) void k_gemm(
    const float* __restrict__ in, const float* __restrict__ Wh,
    const float* __restrict__ Wl, unsigned int* __restrict__ H)
{
    __shared__ __align__(16) unsigned short ldsW[2][64][136];  // 34816 B
    __shared__ __align__(16) unsigned short ldsA[64][136];     // 17408 B

    // W conversion: coalesced 256-B reads along n; packed u32 LDS writes.
    {
        int n  = threadIdx.x & 63;          // lane-consecutive -> coalesced
        int kg = threadIdx.x >> 6;          // 4 k-groups of 32
        #pragma unroll
        for (int m = 0; m < 2; m++) {
            const float* W = m ? Wl : Wh;
            #pragma unroll
            for (int i = 0; i < 32; i += 2) {
                int k = kg * 32 + i;
                float a = W[k * 64 + n];
                float b = W[(k + 1) * 64 + n];
                *(unsigned int*)&ldsW[m][n][k] = packbf(a, b);  // k even: aligned
            }
        }
    }

    // A tile: 64 rows x 128 f32, fully coalesced f32x4 loads, packed LDS writes
    int row0B = blockIdx.x * 64;
    {
        const f32x4* src = (const f32x4*)(in + (size_t)row0B * IN_F);
        #pragma unroll
        for (int i = 0; i < 8; i++) {
            int cch = threadIdx.x + 256 * i;         // 2048 chunks of f32x4
            int row = cch >> 5;                      // 32 chunks per row
            int kc = (cch & 31) * 4;
            int grow = row0B + row;
            f32x4 v = (grow < N_NODES) ? src[cch]
                      : *(const f32x4*)(in + (size_t)(N_NODES - 1) * IN_F + kc);
            unsigned int p0 = packbf(v[0], v[1]);
            unsigned int p1 = packbf(v[2], v[3]);
            *(unsigned int*)&ldsA[row][kc]     = p0;
            *(unsigned int*)&ldsA[row][kc + 2] = p1;
        }
    }
    __syncthreads();

    int wv = threadIdx.x >> 6;
    int lane = threadIdx.x & 63;
    int quad = lane >> 4, c = lane & 15;
    int row0 = row0B + wv * 16;

    bf16x8 afrag[4];
    #pragma unroll
    for (int kb = 0; kb < 4; kb++) {
        BF8 a;
        a.u = *(const u16x8*)&ldsA[wv * 16 + c][kb * 32 + quad * 8];
        afrag[kb] = a.b;
    }

    f32x4 acc[2][4];
    #pragma unroll
    for (int m = 0; m < 2; m++)
        #pragma unroll
        for (int t = 0; t < 4; t++) acc[m][t] = (f32x4){0, 0, 0, 0};

    #pragma unroll
    for (int kb = 0; kb < 4; kb++) {
        #pragma unroll
        for (int t = 0; t < 4; t++) {
            int n = t * 16 + c;
            BF8 bh, bl;
            bh.u = *(const u16x8*)&ldsW[0][n][kb * 32 + quad * 8];
            bl.u = *(const u16x8*)&ldsW[1][n][kb * 32 + quad * 8];
            acc[0][t] = __builtin_amdgcn_mfma_f32_16x16x32_bf16(afrag[kb], bh.b, acc[0][t], 0, 0, 0);
            acc[1][t] = __builtin_amdgcn_mfma_f32_16x16x32_bf16(afrag[kb], bl.b, acc[1][t], 0, 0, 0);
        }
    }

    // C/D: col = t*16 + c, row = quad*4 + r  (proven mapping), packed u32 store
    #pragma unroll
    for (int r = 0; r < 4; r++) {
        int row = row0 + quad * 4 + r;
        if (row >= N_NODES) continue;
        size_t base = (size_t)row * OUT_F + c;
        #pragma unroll
        for (int t = 0; t < 4; t++)
            H[base + t * 16] = packbf(acc[0][t][r], acc[1][t][r]);
    }
}

// ---------------- Kernel B: HAGG + attention scalars s (round-0 verbatim) ----
__global__ __launch_bounds__(256) void k_agg(
    const unsigned int* __restrict__ H, const int* __restrict__ dst,
    const float* __restrict__ ah, const float* __restrict__ al,
    unsigned int* __restrict__ HAGG, f32x4* __restrict__ s)
{
    int lane = threadIdx.x & 63;
    int node = __builtin_amdgcn_readfirstlane(blockIdx.x * 4 + (threadIdx.x >> 6));
    const int* dp = dst + node * DEG;   // 64-B aligned row, scalar loads

    unsigned int hu = H[(size_t)node * 64 + lane];
    float hh = lo_bf(hu);
    float hl = hi_bf(hu);
    float sh = 16.0f * hh;   // DEG * h[i] (self-loop among the 16 dst)
    float sl = 16.0f * hl;

    #pragma unroll
    for (int half = 0; half < 2; half++) {
        unsigned int u[8];
        #pragma unroll
        for (int t = 0; t < 8; t++) {
            int j = dp[half * 8 + t];                 // SGPR
            u[t] = H[(size_t)j * 64 + lane];          // 8 independent loads in flight
        }
        #pragma unroll
        for (int t = 0; t < 8; t++) { sh += lo_bf(u[t]); sl -= hi_bf(u[t]); }
    }
    HAGG[(size_t)node * 64 + lane] = packbf(sh, sl);

    float ph = hh * ah[lane];
    float qh = hh * ah[64 + lane];
    float pl = hl * al[lane];
    float ql = hl * al[64 + lane];
    #pragma unroll
    for (int o = 32; o > 0; o >>= 1) {
        ph += __shfl_xor(ph, o);
        qh += __shfl_xor(qh, o);
        pl += __shfl_xor(pl, o);
        ql += __shfl_xor(ql, o);
    }
    if (lane == 0) s[node] = (f32x4){ph, qh, pl, ql};
}

// ---------------- Kernel C: weighted aggregate + relu6 (round-0 verbatim) ----
__global__ __launch_bounds__(256) void k_out(
    const unsigned int* __restrict__ HAGG, const int* __restrict__ dst,
    const f32x4* __restrict__ s, float* __restrict__ out)
{
    int lane = threadIdx.x & 63;
    int node = __builtin_amdgcn_readfirstlane(blockIdx.x * 4 + (threadIdx.x >> 6));
    const int* dp = dst + node * DEG;

    int jl = dp[lane & 15];                   // lane e<16 owns edge e
    f32x4 si = s[node];                       // wave-uniform
    f32x4 sj = s[jl];
    float xh = si.x + sj.y;                   // p_high[i] + q_high[j]
    float xl = si.z + sj.w;
    float lh = xh > 0.0f ? xh : 0.2f * xh;
    float ll = xl > 0.0f ? xl : 0.2f * xl;
    float wh = __expf(-lh);
    float wl = __expf(-ll);
    float rh = wh, rl = wl;                   // rowsum over RAW exp values
    #pragma unroll
    for (int o = 8; o > 0; o >>= 1) { rh += __shfl_xor(rh, o); rl += __shfl_xor(rl, o); }
    float eh = fminf(wh, 6.0f);               // relu6 on weights
    float el = fminf(wl, 6.0f);

    float acc_h = 0.0f, acc_l = 0.0f;
    #pragma unroll
    for (int half = 0; half < 2; half++) {
        unsigned int u[8];
        float weh[8], wel[8];
        #pragma unroll
        for (int t = 0; t < 8; t++) {
            int j = dp[half * 8 + t];                 // SGPR
            u[t] = HAGG[(size_t)j * 64 + lane];       // 8 independent loads in flight
        }
        #pragma unroll
        for (int t = 0; t < 8; t++) {
            weh[t] = __shfl(eh, half * 8 + t);
            wel[t] = __shfl(el, half * 8 + t);
        }
        #pragma unroll
        for (int t = 0; t < 8; t++) {
            acc_h += weh[t] * lo_bf(u[t]);
            acc_l += wel[t] * hi_bf(u[t]);
        }
    }
    float r = 0.5f * (acc_h / rh + acc_l / rl);
    r = fminf(fmaxf(r, 0.0f), 6.0f);
    out[(size_t)node * 64 + lane] = r;
}

extern "C" void kernel_launch(void* const* d_in, const int* in_sizes, int n_in,
                              void* d_out, int out_size, void* d_ws, size_t ws_size,
                              hipStream_t stream) {
    const float* input = (const float*)d_in[0];
    const int*   edge  = (const int*)d_in[1];     // [2, E]: src then dst
    const float* Wh    = (const float*)d_in[2];
    const float* Wl    = (const float*)d_in[3];
    const float* ah    = (const float*)d_in[4];
    const float* al    = (const float*)d_in[5];
    float* out = (float*)d_out;

    unsigned int* H    = (unsigned int*)d_ws;                    // 25.6 MB
    unsigned int* HAGG = H + (size_t)N_NODES * 64;               // 25.6 MB
    f32x4* s = (f32x4*)(HAGG + (size_t)N_NODES * 64);            // 1.6 MB

    const int* dstp = edge + E_EDGES;

    k_gemm<<<1563, 256, 0, stream>>>(input, Wh, Wl, H);
    k_agg<<<N_NODES / 4, 256, 0, stream>>>(H, dstp, ah, al, HAGG, s);
    k_out<<<N_NODES / 4, 256, 0, stream>>>(HAGG, dstp, s, out);
}